// Round 5
// baseline (146.419 us; speedup 1.0000x reference)
//
#include <hip/hip_runtime.h>

#define NF 26
#define ND 32
#define NPAIR 325                 // NF*(NF-1)/2
#define ROW_F4 (NF * ND / 4)      // 208 float4 per input batch-row
#define OUT_F4 (NPAIR * ND / 4)   // 2600 float4 per output batch-row
#define ROWS_PER_WAVE 8
#define NTHREADS 256
#define ROWS_PER_BLOCK (ROWS_PER_WAVE * NTHREADS / 64)   // 32

typedef float f32x4 __attribute__((ext_vector_type(4)));

// Register-resident interaction: each lane owns one (row, d4) column slice.
// lane = r*8 + d4 : holds in[row, f, 4*d4 .. 4*d4+3] for all 26 f in VGPRs.
// Pair loop is wave-uniform with compile-time register indices -> no LDS,
// no barriers, no divergence.
// Round 5 A/B: plain stores (L2 write-back batching) instead of nontemporal.
__global__ __launch_bounds__(NTHREADS) void interaction_kernel(
    const f32x4* __restrict__ in, f32x4* __restrict__ out)
{
    const int tid  = threadIdx.x;
    const int wave = tid >> 6;
    const int lane = tid & 63;
    const int r    = lane >> 3;   // 0..7: row within this wave's 8 rows
    const int d4   = lane & 7;    // 0..7: float4 column within D=32

    const long row = (long)blockIdx.x * ROWS_PER_BLOCK + wave * ROWS_PER_WAVE + r;

    // Load this lane's column: 26 float4 at 128B stride, all from one base
    // with immediate offsets (f*128 <= 3200 < 4096).
    const f32x4* __restrict__ src = in + row * ROW_F4 + d4;
    f32x4 a[NF];
    #pragma unroll
    for (int f = 0; f < NF; ++f) a[f] = src[f * (ND / 4)];

    // 325 wave-uniform pair products; store offsets compile-time (p*128B).
    f32x4* __restrict__ dst = out + row * OUT_F4 + d4;
    int p = 0;
    #pragma unroll
    for (int i = 0; i < NF; ++i) {
        #pragma unroll
        for (int j = i + 1; j < NF; ++j) {
            dst[p * (ND / 4)] = a[i] * a[j];
            ++p;
        }
    }
}

extern "C" void kernel_launch(void* const* d_in, const int* in_sizes, int n_in,
                              void* d_out, int out_size, void* d_ws, size_t ws_size,
                              hipStream_t stream) {
    const f32x4* in  = (const f32x4*)d_in[0];
    f32x4*       out = (f32x4*)d_out;
    const int B = in_sizes[0] / (NF * ND);          // 16384
    const int blocks = B / ROWS_PER_BLOCK;          // 512
    interaction_kernel<<<blocks, NTHREADS, 0, stream>>>(in, out);
}

// Round 6
// 138.575 us; speedup vs baseline: 1.0566x; 1.0566x over previous
//
#include <hip/hip_runtime.h>

#define NF 26
#define ND 32
#define NPAIR 325                 // NF*(NF-1)/2
#define ROW_F4 (NF * ND / 4)      // 208 float4 per input batch-row
#define OUT_F4 (NPAIR * ND / 4)   // 2600 float4 per output batch-row
#define ROWS_PER_WAVE 8
#define NTHREADS 256
#define ROWS_PER_BLOCK (ROWS_PER_WAVE * NTHREADS / 64)   // 32
#define NBLOCKS 128
#define GROUPS_PER_BLOCK 4        // 16384 / 32 / 128

typedef float f32x4 __attribute__((ext_vector_type(4)));

// Register-resident interaction, persistent-grid variant.
// lane = r*8 + d4 : holds in[row, f, 4*d4 .. 4*d4+3] for all 26 f in VGPRs.
// 128 blocks x 4 waves = 512 resident waves (~2 waves/CU) -> ~4K concurrent
// write streams instead of ~16K: testing DRAM page-locality hypothesis.
// Next group's 26 loads are prefetched into a second register set during
// the store phase (pure registers, no LDS, no barriers).
__global__ __launch_bounds__(NTHREADS) void interaction_kernel(
    const f32x4* __restrict__ in, f32x4* __restrict__ out)
{
    const int tid  = threadIdx.x;
    const int wave = tid >> 6;
    const int lane = tid & 63;
    const int r    = lane >> 3;   // 0..7: row within this wave's 8 rows
    const int d4   = lane & 7;    // 0..7: float4 column within D=32

    // Block handles 4 consecutive 32-row groups: rows [blk*128, blk*128+127].
    const long row0 = (long)blockIdx.x * (ROWS_PER_BLOCK * GROUPS_PER_BLOCK)
                    + wave * ROWS_PER_WAVE + r;

    f32x4 a[NF], b[NF];

    // Prime: load group 0.
    {
        const f32x4* __restrict__ src = in + row0 * ROW_F4 + d4;
        #pragma unroll
        for (int f = 0; f < NF; ++f) a[f] = src[f * (ND / 4)];
    }

    #pragma unroll
    for (int g = 0; g < GROUPS_PER_BLOCK; ++g) {
        const long row = row0 + (long)g * ROWS_PER_BLOCK;
        f32x4* cur = (g & 1) ? b : a;
        f32x4* nxt = (g & 1) ? a : b;

        // Prefetch next group's column into the other register set; the
        // 325 stores below hide the HBM latency (no barriers needed).
        if (g + 1 < GROUPS_PER_BLOCK) {
            const f32x4* __restrict__ src =
                in + (row + ROWS_PER_BLOCK) * ROW_F4 + d4;
            #pragma unroll
            for (int f = 0; f < NF; ++f) nxt[f] = src[f * (ND / 4)];
        }

        // 325 wave-uniform pair products; store offsets compile-time.
        f32x4* __restrict__ dst = out + row * OUT_F4 + d4;
        int p = 0;
        #pragma unroll
        for (int i = 0; i < NF; ++i) {
            #pragma unroll
            for (int j = i + 1; j < NF; ++j) {
                __builtin_nontemporal_store(cur[i] * cur[j], dst + p * (ND / 4));
                ++p;
            }
        }
    }
}

extern "C" void kernel_launch(void* const* d_in, const int* in_sizes, int n_in,
                              void* d_out, int out_size, void* d_ws, size_t ws_size,
                              hipStream_t stream) {
    const f32x4* in  = (const f32x4*)d_in[0];
    f32x4*       out = (f32x4*)d_out;
    interaction_kernel<<<NBLOCKS, NTHREADS, 0, stream>>>(in, out);
}